// Round 4
// baseline (310.758 us; speedup 1.0000x reference)
//
#include <hip/hip_runtime.h>

// Maxwell RNN scan: gamma_n = (1-h_n) gamma_{n-1} + h_n eps_n, h = 0.5*dt
// sig_n = 2.5*eps_n - gamma_{n-1}   (pre-update gamma)
//
// Persistent-block, cross-row software-pipelined version.
// Rows are independent, so each block owns ROWS_PER_BLOCK consecutive rows
// and double-buffers in REGISTERS: while row r is scanned/replayed/stored,
// row r+1's global loads are already in flight. This hides the HBM load
// latency that kept all one-shot-block variants (R0-R3) at ~2.3 TB/s.
//
// 1024 threads x 8 elems = one full 8192 row per iteration -> gamma_in = 0
// every row, single scan sequence, one __syncthreads per row (wA/wB are
// parity double-buffered so the next row's barrier covers the WAR hazard).
// Plain stores (measured: nontemporal amplifies HBM writes 1.5-2.6x).

constexpr int   T_LEN   = 8192;
constexpr int   THREADS = 1024;
constexpr int   NWAVES  = THREADS / 64;   // 16
constexpr int   V       = 8;              // elements per thread (1024*8 = 8192)
constexpr int   ROWS_PB = 8;              // rows per persistent block
constexpr float KCOEF   = 0.5f;           // E_MOD / ETA

typedef float f32x4 __attribute__((ext_vector_type(4)));

__global__ __launch_bounds__(THREADS, 2) void maxwell_scan_kernel(
    const float* __restrict__ eps, const float* __restrict__ dtv,
    float* __restrict__ out)
{
    const int tid  = threadIdx.x;
    const int lane = tid & 63;
    const int wid  = tid >> 6;

    __shared__ float wA[2][NWAVES], wB[2][NWAVES];

    const size_t base0 = (size_t)blockIdx.x * ROWS_PB * T_LEN + (size_t)tid * V;
    const float* ep = eps + base0;
    const float* dp = dtv + base0;
    float*       op = out + base0;

    // ---- Prologue: issue row 0's loads (the only exposed HBM latency).
    f32x4 re0 = *(const f32x4*)(ep);
    f32x4 re1 = *(const f32x4*)(ep + 4);
    f32x4 rd0 = *(const f32x4*)(dp);
    f32x4 rd1 = *(const f32x4*)(dp + 4);

    for (int r = 0; r < ROWS_PB; ++r) {
        // ---- Consume the in-flight row (compiler waits vmcnt here).
        float ev[V] = {re0.x, re0.y, re0.z, re0.w, re1.x, re1.y, re1.z, re1.w};
        float hv[V] = {rd0.x * KCOEF, rd0.y * KCOEF, rd0.z * KCOEF, rd0.w * KCOEF,
                       rd1.x * KCOEF, rd1.y * KCOEF, rd1.z * KCOEF, rd1.w * KCOEF};

        // ---- Immediately issue next row's loads; they fly under this row's
        // scan/replay/store. (Uniform branch; last iteration skips.)
        ep += T_LEN; dp += T_LEN;
        if (r + 1 < ROWS_PB) {
            re0 = *(const f32x4*)(ep);
            re1 = *(const f32x4*)(ep + 4);
            rd0 = *(const f32x4*)(dp);
            rd1 = *(const f32x4*)(dp + 4);
        }

        // ---- Compose this thread's chunk: gamma_out = A*gamma_in + B.
        float A = 1.0f, Bc = 0.0f;
        #pragma unroll
        for (int j = 0; j < V; ++j) {
            float a = 1.0f - hv[j];
            Bc = a * Bc + hv[j] * ev[j];
            A *= a;
        }

        // ---- Inclusive wave scan under composition (later ∘ earlier).
        float sa = A, sb = Bc;
        #pragma unroll
        for (int off = 1; off < 64; off <<= 1) {
            float pa = __shfl_up(sa, off, 64);
            float pb = __shfl_up(sb, off, 64);
            if (lane >= off) {
                sb = sa * pb + sb;
                sa = sa * pa;
            }
        }
        const int p = r & 1;
        if (lane == 63) { wA[p][wid] = sa; wB[p][wid] = sb; }
        __syncthreads();

        // ---- Exclusive-within-wave transform.
        float xa = __shfl_up(sa, 1, 64);
        float xb = __shfl_up(sb, 1, 64);
        if (lane == 0) { xa = 1.0f; xb = 0.0f; }

        // ---- B-prefix over preceding waves (gamma_in = 0 per row, so only
        // the B component is ever needed). Wave-uniform tiny loop.
        float pfb = 0.0f;
        for (int w = 0; w < wid; ++w) pfb = wA[p][w] * pfb + wB[p][w];

        // gamma entering this thread's chunk.
        float g = xa * pfb + xb;

        // ---- Replay: emit sigma, advance gamma. Plain stores.
        f32x4 sg;
        #pragma unroll
        for (int j = 0; j < 4; ++j) {
            sg[j] = 2.5f * ev[j] - g;           // E_INF*e + E*(e - g)
            g = g + hv[j] * (ev[j] - g);        // g += dt*k*(e - g)
        }
        *(f32x4*)(op) = sg;
        #pragma unroll
        for (int j = 0; j < 4; ++j) {
            sg[j] = 2.5f * ev[4 + j] - g;
            g = g + hv[4 + j] * (ev[4 + j] - g);
        }
        *(f32x4*)(op + 4) = sg;
        op += T_LEN;
    }
}

extern "C" void kernel_launch(void* const* d_in, const int* in_sizes, int n_in,
                              void* d_out, int out_size, void* d_ws, size_t ws_size,
                              hipStream_t stream) {
    const float* eps = (const float*)d_in[0];
    const float* dtv = (const float*)d_in[1];
    float* out = (float*)d_out;
    const int B = in_sizes[0] / T_LEN;        // 4096 rows
    const int blocks = B / ROWS_PB;           // 512 persistent blocks (2/CU)
    maxwell_scan_kernel<<<blocks, THREADS, 0, stream>>>(eps, dtv, out);
}